// Round 12
// baseline (53.925 us; speedup 1.0000x reference)
//
#include <hip/hip_runtime.h>
#include <math.h>

// Problem constants (fixed by the reference)
#define B_    16
#define F_    32
#define NP_   128   // rows per (b,f) panel
#define D_    512
#define P_    16
#define KC    32            // K-chunk in floats (128 B per row per chunk)
#define NCH   16            // chunks; each = 1 MFMA k-step (K=32)
#define ROWS  64            // rows per sub-block
#define BUFW  (ROWS * KC)   // 2048 floats = 8 KB per ring buffer

typedef __attribute__((ext_vector_type(8))) short  short8;   // 8 bf16 = 4 VGPR
typedef __attribute__((ext_vector_type(4))) float  floatx4;  // 16x16 acc

union Frag { short8 v; unsigned int u[4]; };

__device__ inline unsigned int cvt_pk_bf16(float lo, float hi) {
    unsigned int r;
    asm volatile("v_cvt_pk_bf16_f32 %0, %1, %2" : "=v"(r) : "v"(lo), "v"(hi));
    return r;
}

// grid 1024 = (b,f) x 2 row-halves; 512 thr = 8 waves = 4 M-tiles x 2 N-tiles.
// 16x16x32 MFMA: acc=4, no K-parity merge. VGPR<=64 -> 4 blocks/CU (32 waves,
// 4 independent barrier domains/CU — the axis R9-R11 never moved).
// vmcnt bookkeeping per wave: STAGE=1 op, B-chunk=2 ops, B prefetch 2 deep:
//   prologue: S0 S1 S2 | B0a B0b B1a B1b
//   iter c:   wait -> barrier -> STAGE(c+3) -> load B(c+2) -> compute(c)
//   waits: c=0: vmcnt(2); c=1..13: vmcnt(3); c=14: vmcnt(2); c=15: vmcnt(0)
__global__ __launch_bounds__(512, 8)
void pd_kernel(const float* __restrict__ ts,
               const float* __restrict__ W,
               const float* __restrict__ bias,
               float* __restrict__ out, int T)
{
    __shared__ float smem[4 * BUFW];   // 32 KB ring; reused by epilogue

    const int tid  = threadIdx.x;
    const int lane = tid & 63;
    const int wave = tid >> 6;        // 0..7
    const int nt   = wave & 1;        // N-tile: e in [16*nt, 16*nt+16)
    const int mt   = wave >> 1;       // M-tile: local rows [16*mt, 16*mt+16)

    // XCD-aware id: d = (b&7) | ((f*2+s) << 3) | ((b>>3) << 9)
    const int d = blockIdx.x;
    const int b   = (d & 7) | ((d >> 9) << 3);
    const int idx = (d >> 3) & 63;
    const int f   = idx >> 1;
    const int s   = idx & 1;          // row-half of the panel
    const float* __restrict__ tsb =
        ts + (((size_t)b * F_ + f) * NP_ + s * ROWS) * D_;

    // Stage chunk cc into ring buf cc&3: 512 slots (64 rows x 8 quads), one
    // per thread. Slot(rr,ql) holds global quad ql^(rr&7) (bijective per row).
    const int rr = tid >> 3;
    const int qg = (tid & 7) ^ (rr & 7);
    auto STAGE = [&](int cc) {
        const float* src = tsb + rr * D_ + cc * KC + (qg << 2);
        float* dst = smem + (cc & 3) * BUFW + (tid << 2);
        __builtin_amdgcn_global_load_lds(
            (const __attribute__((address_space(1))) unsigned int*)src,
            (__attribute__((address_space(3))) unsigned int*)dst,
            16, 0, 0);
    };

    // B addressing: lane -> e = nt*16 + (lane&15), k-group kg = lane>>4 (8 k's)
    const int e_lane = nt * 16 + (lane & 15);
    const int kg     = lane >> 4;
    const float* wB  = W + (size_t)e_lane * D_ + kg * 8;

    // A addressing: local row = mt*16 + (lane&15); quads 2kg, 2kg+1; XOR swz
    const int arow = mt * 16 + (lane & 15);
    const int asw  = arow & 7;
    const int aq   = kg * 2;

    // ---- prologue: DMA first, then B prefetch (order pinned for vmcnt math)
    STAGE(0); STAGE(1); STAGE(2);
    __builtin_amdgcn_sched_barrier(0);
    float4 bA[2], bB[2];                       // B double-buffer (slot = c&1)
    bA[0] = *(const float4*)(wB);       bB[0] = *(const float4*)(wB + 4);
    bA[1] = *(const float4*)(wB + 32);  bB[1] = *(const float4*)(wB + 36);
    __builtin_amdgcn_sched_barrier(0);

    floatx4 acc;
#pragma unroll
    for (int r = 0; r < 4; ++r) acc[r] = 0.f;

    // ---- main loop (fully unrolled: all slot indices compile-time)
#pragma unroll
    for (int c = 0; c < NCH; ++c) {
        if (c == 0)       asm volatile("s_waitcnt vmcnt(2)\n\ts_barrier" ::: "memory");
        else if (c <= 13) asm volatile("s_waitcnt vmcnt(3)\n\ts_barrier" ::: "memory");
        else if (c == 14) asm volatile("s_waitcnt vmcnt(2)\n\ts_barrier" ::: "memory");
        else              asm volatile("s_waitcnt vmcnt(0)\n\ts_barrier" ::: "memory");
        __builtin_amdgcn_sched_barrier(0);

        // consume B(c) into a fragment (data guaranteed by the wait above)
        Frag bb;
        bb.u[0] = cvt_pk_bf16(bA[c & 1].x, bA[c & 1].y);
        bb.u[1] = cvt_pk_bf16(bA[c & 1].z, bA[c & 1].w);
        bb.u[2] = cvt_pk_bf16(bB[c & 1].x, bB[c & 1].y);
        bb.u[3] = cvt_pk_bf16(bB[c & 1].z, bB[c & 1].w);

        if (c + 3 < NCH) STAGE(c + 3);                 // 1 VMEM op
        if (c + 2 < NCH) {                             // 2 VMEM ops
            bA[c & 1] = *(const float4*)(wB + (c + 2) * KC);
            bB[c & 1] = *(const float4*)(wB + (c + 2) * KC + 4);
        }

        const float4* rowp = (const float4*)(smem + (c & 3) * BUFW + arow * KC);
        const float4 lo = rowp[aq ^ asw];
        const float4 hi = rowp[(aq + 1) ^ asw];
        Frag a;
        a.u[0] = cvt_pk_bf16(lo.x, lo.y);
        a.u[1] = cvt_pk_bf16(lo.z, lo.w);
        a.u[2] = cvt_pk_bf16(hi.x, hi.y);
        a.u[3] = cvt_pk_bf16(hi.z, hi.w);
        acc = __builtin_amdgcn_mfma_f32_16x16x32_bf16(a.v, bb.v, acc, 0, 0, 0);
    }

    // ---- C-write + bias/exp fused. 16x16 C map: col=lane&15 (=e_lane-16nt),
    // row = (lane>>4)*4 + r. Region [0,2145) floats = buf0+buf1-head; loop
    // laggards only read buf3 (chunk 15) -> disjoint, race-free.
    {
        const float bv = bias[e_lane];
#pragma unroll
        for (int r = 0; r < 4; ++r) {
            const int nloc = mt * 16 + kg * 4 + r;
            float v = acc[r] + bv;
            if (e_lane >= P_) v = fmaxf(expf(v), 1e-6f);  // wave-uniform branch
            smem[nloc * 33 + e_lane] = v;
        }
    }

    // ---- boundary row (sub 0 only): raw[64][e] partials, 512 threads x 32 MAC
    // (issued after the loop's final vmcnt(0) -> doesn't perturb counting)
    if (s == 0) {
        const int e   = tid & 31;
        const int seg = tid >> 5;                     // 16 segments x 32 k
        const float* tr = tsb + 64 * D_ + seg * 32;   // panel row 64
        const float* wr = W + (size_t)e * D_ + seg * 32;
        float psum = 0.f;
#pragma unroll
        for (int j = 0; j < 8; ++j) {
            const float4 x = ((const float4*)tr)[j];
            const float4 w = ((const float4*)wr)[j];
            psum += x.x * w.x + x.y * w.y + x.z * w.z + x.w * w.w;
        }
        smem[2176 + tid] = psum;                      // [2176,2688): buf1 area
    }
    __syncthreads();

    if (s == 0 && tid < 32) {                         // finalize row 64
        float v = 0.f;
#pragma unroll
        for (int j = 0; j < 16; ++j) v += smem[2176 + j * 32 + tid];
        v += bias[tid];
        if (tid >= P_) v = fmaxf(expf(v), 1e-6f);
        smem[64 * 33 + tid] = v;
    }
    __syncthreads();

    // ---- gather. sub 0: t in [0,520) from rows 0..64; sub 1: [520,T) from
    // rows 64..127 (local 0..63). out[b,t,f] = sum raw[n][.] / cnt
    const int TF = T * F_;
    const size_t halfoff = (size_t)B_ * TF;
    const int t0    = s ? 520 : 0;
    const int tcnt  = s ? (T - 520) : 520;
    const int rbase = s ? 64 : 0;
    for (int item = tid; item < 2 * tcnt; item += 512) {
        const int half = (item >= tcnt) ? 1 : 0;
        const int t    = t0 + item - half * tcnt;
        const int nmax = min(NP_ - 1, t >> 3);
        const int nmin = (t > 8) ? ((t - 8) >> 3) : 0;
        float sum = 0.f;
        const int cnt = nmax - nmin + 1;
        for (int nn = nmin; nn <= nmax; ++nn)
            sum += smem[(nn - rbase) * 33 + (half << 4) + (t - (nn << 3))];
        const float r = (cnt > 0) ? sum / (float)cnt : 0.f;
        out[(size_t)half * halfoff + (size_t)b * TF + (size_t)t * F_ + f] = r;
    }
}

extern "C" void kernel_launch(void* const* d_in, const int* in_sizes, int n_in,
                              void* d_out, int out_size, void* d_ws, size_t ws_size,
                              hipStream_t stream)
{
    const float* ts   = (const float*)d_in[0];
    const float* W    = (const float*)d_in[1];
    const float* bias = (const float*)d_in[2];
    float* out = (float*)d_out;

    // T derived on host from out_size = 2 * B * T * F
    const int T = out_size / (2 * B_ * F_);

    dim3 grid(B_ * F_ * 2);   // 1024 blocks: (b,f) x row-half, XCD-encoded
    dim3 block(512);
    pd_kernel<<<grid, block, 0, stream>>>(ts, W, bias, out, T);
}

// Round 13
// 43.911 us; speedup vs baseline: 1.2280x; 1.2280x over previous
//
#include <hip/hip_runtime.h>
#include <math.h>

// Problem constants (fixed by the reference)
#define B_    16
#define F_    32
#define NP_   128   // rows per (b,f) panel
#define D_    512
#define P_    16
#define KC    32            // K-chunk in floats (128 B per row per chunk)
#define NCH   16            // chunks; each = 1 MFMA k-step (K=32)
#define WBUF  512           // floats per (wave, ring slot): 16 rows x 32
#define WRING (4 * WBUF)    // 2048 floats (8 KB) private ring per wave

typedef __attribute__((ext_vector_type(8))) short  short8;   // 8 bf16
typedef __attribute__((ext_vector_type(4))) float  floatx4;  // 16x16 acc

union Frag { short8 v; unsigned int u[4]; };

__device__ inline unsigned int cvt_pk_bf16(float lo, float hi) {
    unsigned int r;
    asm volatile("v_cvt_pk_bf16_f32 %0, %1, %2" : "=v"(r) : "v"(lo), "v"(hi));
    return r;
}

// 512 blocks (one per (b,f), XCD-encoded), 512 threads = 8 waves.
// Wave w owns rows [16w,16w+16): stages them into a PRIVATE 4-deep LDS ring
// and computes all 32 e's itself (2x mfma_16x16x32 per chunk, B streamed).
// => ZERO barriers in the main loop; 16 independent self-paced wave
// pipelines per CU (vmcnt is per-wave). Issue order per iter (pinned):
//   wait -> load B(c+2) [4 ops] -> STAGE(c+3) [2 ops] -> compute(c)
// prologue: S0 S1 B0 B1 S2. waits: c=0:vmcnt(6); c=1..13:vmcnt(8);
// c=14:vmcnt(6); c=15:vmcnt(0).  (youngest needed at iter c = B_c.)
__global__ __launch_bounds__(512, 4)
void pd_kernel(const float* __restrict__ ts,
               const float* __restrict__ W,
               const float* __restrict__ bias,
               float* __restrict__ out, int T)
{
    __shared__ float smem[8 * WRING];   // 64 KB; reused by epilogue

    const int tid  = threadIdx.x;
    const int lane = tid & 63;
    const int w    = tid >> 6;        // wave 0..7 -> rows [16w, 16w+16)

    // XCD-aware block-id encoding (proven: WRITE_SIZE at ideal ~4.1 MB)
    const int d = blockIdx.x;
    const int b = (d & 7) | ((d >> 8) << 3);
    const int f = (d >> 3) & 31;
    const float* __restrict__ tsb =
        ts + (((size_t)b * F_ + f) * NP_ + w * 16) * D_;   // wave's 16 rows
    float* const wbase = smem + w * WRING;

    // STAGE chunk cc into private ring slot cc&3: 2 wave-instructions of
    // 1 KB each. slot(r,ql) holds global quad ql^(r&7) (bijective per row;
    // proven conflict-free family, R5/R6).
    auto STAGE = [&](int cc) {
#pragma unroll
        for (int i = 0; i < 2; ++i) {
            const int slot = i * 64 + lane;        // 0..127 (16 rows x 8 quads)
            const int r  = slot >> 3;
            const int qg = (slot & 7) ^ (r & 7);
            const float* src = tsb + r * D_ + cc * KC + (qg << 2);
            float* dst = wbase + (cc & 3) * WBUF + (slot << 2);
            __builtin_amdgcn_global_load_lds(
                (const __attribute__((address_space(1))) unsigned int*)src,
                (__attribute__((address_space(3))) unsigned int*)dst,
                16, 0, 0);
        }
    };

    // B addressing: lane -> e0 = lane&15 (nt0) / 16+e0 (nt1), kg = lane>>4
    const int e0l = lane & 15;
    const int kg  = lane >> 4;
    const float* wB0 = W + (size_t)e0l * D_ + kg * 8;          // mu rows
    const float* wB1 = W + (size_t)(16 + e0l) * D_ + kg * 8;   // sigma rows

    // A addressing: row r = lane&15 of wave's tile; quads 2kg, 2kg+1; XOR swz
    const int ar  = lane & 15;
    const int asw = ar & 7;
    const int aq  = kg * 2;

    // ---- prologue (order pinned for per-wave vmcnt arithmetic)
    float4 b0lo[3], b0hi[3], b1lo[3], b1hi[3];   // B triple-buffer, slot c%3
    STAGE(0);
    STAGE(1);
    __builtin_amdgcn_sched_barrier(0);
    b0lo[0] = *(const float4*)(wB0);      b0hi[0] = *(const float4*)(wB0 + 4);
    b1lo[0] = *(const float4*)(wB1);      b1hi[0] = *(const float4*)(wB1 + 4);
    b0lo[1] = *(const float4*)(wB0 + 32); b0hi[1] = *(const float4*)(wB0 + 36);
    b1lo[1] = *(const float4*)(wB1 + 32); b1hi[1] = *(const float4*)(wB1 + 36);
    __builtin_amdgcn_sched_barrier(0);
    STAGE(2);
    __builtin_amdgcn_sched_barrier(0);

    floatx4 acc0, acc1;
#pragma unroll
    for (int r = 0; r < 4; ++r) { acc0[r] = 0.f; acc1[r] = 0.f; }

    // ---- main loop: NO barriers; fully unrolled (static ring/slot indices)
#pragma unroll
    for (int c = 0; c < NCH; ++c) {
        if (c == 0)       asm volatile("s_waitcnt vmcnt(6)" ::: "memory");
        else if (c <= 13) asm volatile("s_waitcnt vmcnt(8)" ::: "memory");
        else if (c == 14) asm volatile("s_waitcnt vmcnt(6)" ::: "memory");
        else              asm volatile("s_waitcnt vmcnt(0)" ::: "memory");
        __builtin_amdgcn_sched_barrier(0);

        if (c + 2 < NCH) {          // 4 VMEM ops into reg slot (c+2)%3
            const int sl = (c + 2) % 3;
            b0lo[sl] = *(const float4*)(wB0 + (c + 2) * KC);
            b0hi[sl] = *(const float4*)(wB0 + (c + 2) * KC + 4);
            b1lo[sl] = *(const float4*)(wB1 + (c + 2) * KC);
            b1hi[sl] = *(const float4*)(wB1 + (c + 2) * KC + 4);
        }
        __builtin_amdgcn_sched_barrier(0);
        if (c + 3 < NCH) STAGE(c + 3);   // 2 VMEM ops
        __builtin_amdgcn_sched_barrier(0);

        // consume B(c) (covered by the wait above)
        const int sc = c % 3;
        Frag bb0, bb1;
        bb0.u[0] = cvt_pk_bf16(b0lo[sc].x, b0lo[sc].y);
        bb0.u[1] = cvt_pk_bf16(b0lo[sc].z, b0lo[sc].w);
        bb0.u[2] = cvt_pk_bf16(b0hi[sc].x, b0hi[sc].y);
        bb0.u[3] = cvt_pk_bf16(b0hi[sc].z, b0hi[sc].w);
        bb1.u[0] = cvt_pk_bf16(b1lo[sc].x, b1lo[sc].y);
        bb1.u[1] = cvt_pk_bf16(b1lo[sc].z, b1lo[sc].w);
        bb1.u[2] = cvt_pk_bf16(b1hi[sc].x, b1hi[sc].y);
        bb1.u[3] = cvt_pk_bf16(b1hi[sc].z, b1hi[sc].w);

        // A fragment from private ring (swizzled ds_read_b128 x2)
        const float* rp = wbase + (c & 3) * WBUF + ar * KC;
        const float4 lo = *(const float4*)(rp + ((aq     ^ asw) << 2));
        const float4 hi = *(const float4*)(rp + (((aq+1) ^ asw) << 2));
        Frag a;
        a.u[0] = cvt_pk_bf16(lo.x, lo.y);
        a.u[1] = cvt_pk_bf16(lo.z, lo.w);
        a.u[2] = cvt_pk_bf16(hi.x, hi.y);
        a.u[3] = cvt_pk_bf16(hi.z, hi.w);

        acc0 = __builtin_amdgcn_mfma_f32_16x16x32_bf16(a.v, bb0.v, acc0, 0, 0, 0);
        acc1 = __builtin_amdgcn_mfma_f32_16x16x32_bf16(a.v, bb1.v, acc1, 0, 0, 0);
    }

    // ---- epilogue: all waves done -> safe to repurpose LDS
    __syncthreads();
    {
        // 16x16 C map: col = lane&15, row = kg*4 + r (verified R12)
        const float bv0 = bias[e0l];
        const float bv1 = bias[16 + e0l];
#pragma unroll
        for (int r = 0; r < 4; ++r) {
            const int nloc = w * 16 + kg * 4 + r;
            smem[nloc * 33 + e0l] = acc0[r] + bv0;
            smem[nloc * 33 + 16 + e0l] = fmaxf(expf(acc1[r] + bv1), 1e-6f);
        }
    }
    __syncthreads();

    // gather: out[b,t,f] = sum_{n: t-8n in [0,16)} raw[n][.] / cnt
    const int TF = T * F_;
    const size_t halfoff = (size_t)B_ * TF;
    for (int item = tid; item < 2 * T; item += 512) {
        const int half = (item >= T) ? 1 : 0;
        const int t    = item - half * T;
        const int nmax = min(NP_ - 1, t >> 3);
        const int nmin = (t > 8) ? ((t - 8) >> 3) : 0;
        float sum = 0.f;
        const int cnt = nmax - nmin + 1;
        for (int nn = nmin; nn <= nmax; ++nn)
            sum += smem[nn * 33 + (half << 4) + (t - (nn << 3))];
        const float r = (cnt > 0) ? sum / (float)cnt : 0.f;
        out[(size_t)half * halfoff + (size_t)b * TF + (size_t)t * F_ + f] = r;
    }
}

extern "C" void kernel_launch(void* const* d_in, const int* in_sizes, int n_in,
                              void* d_out, int out_size, void* d_ws, size_t ws_size,
                              hipStream_t stream)
{
    const float* ts   = (const float*)d_in[0];
    const float* W    = (const float*)d_in[1];
    const float* bias = (const float*)d_in[2];
    float* out = (float*)d_out;

    // T derived on host from out_size = 2 * B * T * F
    const int T = out_size / (2 * B_ * F_);

    dim3 grid(B_ * F_);   // 512 blocks, one per (b, f), XCD-encoded id
    dim3 block(512);
    pd_kernel<<<grid, block, 0, stream>>>(ts, W, bias, out, T);
}